// Round 8
// baseline (195.984 us; speedup 1.0000x reference)
//
#include <hip/hip_runtime.h>

// CTC loss forward. logits (T,N,C) fp32 log-probs, labels (N,S) int32 in
// [1,C), prediction/target sizes (N,).
//
// R15: steady-state memory-queue repair. R11..R14 post-mortem: four
// structures plateau at ours ~= 38 +- 2us vs a ~24us model; the residual is
// the fused kernel's per-chunk schedule: store() runs first (memory queue
// EMPTY for ~700cyc), then loads issue, then __syncthreads drains them --
// queue empties twice per chunk. Fixes (combined for the first time):
//  (1) exact 7-wave row partition (wave0 rows 0..9, waves1..6 9 rows each;
//      64 exact) -- kills the 9% duplicate clamp-row over-issue;
//  (2) double-buffered u-regs (uA/uB): loads issue at phase TOP into the
//      buffer not being consumed this phase (+80 VGPR, free at 1 block/CU);
//  (3) counted-wait RING_BARRIER (lgkmcnt(0)-only + raw s_barrier, verified
//      correct in R12): top-issued loads stay in flight across the barrier.
// Together: the per-CU memory queue never empties in steady state.
//
// Structure (R10..R14, verified absmax 0.0): one block per batch item n,
// 8 waves; waves 1..7 gather/compact 64-row chunks into a 2x64-row LDS ring
// (coalesced float4 -> named regs -> private LDS stage -> cross-lane
// ds_read at labels -> exp(+BOOST) -> 256B compact row); wave 0 (at
// s_setprio(1)) runs the serial alpha chain from the ring; per-block loss
// published via device-scope atomics (val, threadfence, MAGIC flag); block0
// parallel-polls the 256 flags, reduces, writes out[0] (deadlock-free:
// only block 0 waits; writers are independent and exit). Logits read once.
// Alpha in LINEAR space: per step one DPP wave_shr1 + 5 VALU ops,
// wave-uniform renorm every 16 steps (DPP-max butterfly, logged into
// logscale); emissions carry +BOOST/step (un-done at the end); validity
// masks folded in per step.
//
// Hazard audit for (3): ring WAR is two barriers deep (chain consumes its
// ds_reads into registers before its barrier); stage + u-regs wave-private;
// lgkmcnt(0) publishes all ds_writes before each s_barrier.
//
// Workspace: ws[0..255] = loss values (atomic), ws_u32[256..511] = flags.

constexpr int T = 512, N = 256, C = 256, S = 48;
constexpr int CH  = 64;                // t-rows per chunk
constexpr int NCH = T / CH;            // 8 chunks
constexpr float BOOST = 4.0f;          // per-live-step emission boost (e^4)
constexpr unsigned MAGIC = 0x9E3779B9u;  // flag value (!= plausible poison)

__device__ __forceinline__ float wave_shr1(float v, float fill) {
  int r = __builtin_amdgcn_update_dpp(__float_as_int(fill), __float_as_int(v),
                                      0x138, 0xf, 0xf, false);  // wave_shr1
  return __int_as_float(r);
}

#define DPP_MAX(v, ctrl)                                                     \
  fmaxf(v, __int_as_float(__builtin_amdgcn_update_dpp(                       \
               __float_as_int(v), __float_as_int(v), (ctrl), 0xf, 0xf, false)))

// max over 64 lanes, wave-uniform result (alpha >= 0, old-value fallback on
// bcast-inactive lanes is safe).
__device__ __forceinline__ float wavemax(float v) {
  v = DPP_MAX(v, 0x111);               // row_shr:1
  v = DPP_MAX(v, 0x112);               // row_shr:2
  v = DPP_MAX(v, 0x114);               // row_shr:4
  v = DPP_MAX(v, 0x118);               // row_shr:8
  v = DPP_MAX(v, 0x142);               // row_bcast:15
  v = DPP_MAX(v, 0x143);               // row_bcast:31 -> lane 63 = full max
  return __int_as_float(__builtin_amdgcn_readlane(__float_as_int(v), 63));
}

// One 16-step chain group from LDS column PBASE (stride 64 floats/row).
// TG0 = absolute t of d==0; DSTART = 0 normally, 1 for the t=0 slot.
// Renorm (exact bookkeeping) after every group: growth/step <= 3e^4, so
// 16 steps from max~1 stays < 1e36 < fp32 inf.
#define CHAIN_GROUP(PBASE, TG0, DSTART)                                      \
  {                                                                          \
    float e[16];                                                             \
    _Pragma("unroll")                                                        \
    for (int d = (DSTART); d < 16; ++d) e[d] = (PBASE)[(size_t)d * 64];      \
    if ((TG0) + 16 <= Tin) {           /* fast path: all steps live */       \
      _Pragma("unroll")                                                      \
      for (int d = (DSTART); d < 16; ++d) {                                  \
        const float v_ = e[d];                                               \
        const float blank_ = __int_as_float(                                 \
            __builtin_amdgcn_readlane(__float_as_int(v_), 63));              \
        const float eb_ = valid0 ? blank_ : 0.0f;                            \
        const float el_ = valid1 ? v_ : 0.0f;                                \
        const float a1p_ = wave_shr1(a1, 0.0f);                              \
        const float u_ = a1 + a0;          /* off the DPP dependency */      \
        a0 = (a0 + a1p_) * eb_;                                              \
        a1 = fmaf(a1p_, skipf, u_) * el_;                                    \
      }                                                                      \
    } else {                           /* tail: per-step freeze */           \
      _Pragma("unroll")                                                      \
      for (int d = (DSTART); d < 16; ++d) {                                  \
        const float v_ = e[d];                                               \
        const float blank_ = __int_as_float(                                 \
            __builtin_amdgcn_readlane(__float_as_int(v_), 63));              \
        const float eb_ = valid0 ? blank_ : 0.0f;                            \
        const float el_ = valid1 ? v_ : 0.0f;                                \
        const float a1p_ = wave_shr1(a1, 0.0f);                              \
        const float u_ = a1 + a0;                                            \
        const float na0_ = (a0 + a1p_) * eb_;                                \
        const float na1_ = fmaf(a1p_, skipf, u_) * el_;                      \
        if ((TG0) + d < Tin) { a0 = na0_; a1 = na1_; }                       \
      }                                                                      \
    }                                                                        \
    {                                                                        \
      float m_ = fmaxf(wavemax(fmaxf(a0, a1)), 1e-30f);                      \
      const float inv_ = __builtin_amdgcn_rcpf(m_);                          \
      a0 *= inv_; a1 *= inv_;                                                \
      logscale -= __logf(inv_);          /* log exactly what we applied */   \
    }                                                                        \
  }

// LDS-publish barrier that does NOT drain vmcnt: in-flight global loads
// (wave-private register destinations) survive the chunk boundary.
#define RING_BARRIER()                                                       \
  do {                                                                       \
    asm volatile("s_waitcnt lgkmcnt(0)" ::: "memory");                       \
    __builtin_amdgcn_s_barrier();                                            \
  } while (0)

__launch_bounds__(512, 1)
__global__ void ctc_fused_kernel(const float* __restrict__ lp,
                                 const int*  __restrict__ labels,
                                 const int*  __restrict__ in_len,
                                 const int*  __restrict__ tgt_len,
                                 float* __restrict__ ws,
                                 float* __restrict__ out) {
  __shared__ float ring[2][CH][64];    // compact rows, double buffer: 32 KB
  __shared__ float stage[7][2][C];     // per-gather-wave row staging: 14 KB
  __shared__ float partial[4];         // block-0 reduce scratch

  const int n    = blockIdx.x;
  const int lane = threadIdx.x & 63;
  const int wid  = threadIdx.x >> 6;

  // lab doubles as the gather column: labels for lane<48, blank (0) beyond.
  const int lab      = (lane < S) ? labels[n * S + lane] : 0;
  const int lab_prev = __shfl_up(lab, 1);
  const bool skip   = (lab != 0) && ((lane == 0) || (lab != lab_prev));
  const float skipf = skip ? 1.0f : 0.0f;
  const bool valid0 = (lane <= S);     // pos 2i     in [0, 2S]
  const bool valid1 = (lane <  S);     // pos 2i + 1 in [0, 2S]
  const int Tin = in_len[n];
  const int tl  = tgt_len[n];

  // Exact row partition: wave 0 owns rows 0..9 (10), waves 1..6 own 9 rows
  // each starting at 9*gw+1. 10 + 6*9 = 64 = CH, zero duplicates.
  const int gw   = wid - 1;            // gather-wave index 0..6 (wid>0)
  const int row0 = (gw == 0) ? 0 : (9 * gw + 1);
  const bool xtra = (gw == 0);         // wave-uniform: 10th row present
  const size_t rstride = (size_t)N * C;

  // Chain wave gets issue priority over co-resident gather waves: its
  // serial DPP chain is the latency-critical path per chunk.
  if (wid == 0) __builtin_amdgcn_s_setprio(1);

  // Two NAMED register buffers carried across barriers (wave-private).
  float4 uA0{}, uA1{}, uA2{}, uA3{}, uA4{}, uA5{}, uA6{}, uA7{}, uA8{}, uA9{};
  float4 uB0{}, uB1{}, uB2{}, uB3{}, uB4{}, uB5{}, uB6{}, uB7{}, uB8{}, uB9{};

  // issue this wave's coalesced row loads for chunk cc into one buffer
  // (regs land later; per-reg vmcnt waits sit in front of uses in store).
  auto loadbuf = [&](int cc, float4& v0, float4& v1, float4& v2, float4& v3,
                     float4& v4, float4& v5, float4& v6, float4& v7,
                     float4& v8, float4& v9) {
    const float* base =
        lp + ((size_t)(cc * CH + row0) * N + n) * C + lane * 4;
    v0 = *reinterpret_cast<const float4*>(base + 0 * rstride);
    v1 = *reinterpret_cast<const float4*>(base + 1 * rstride);
    v2 = *reinterpret_cast<const float4*>(base + 2 * rstride);
    v3 = *reinterpret_cast<const float4*>(base + 3 * rstride);
    v4 = *reinterpret_cast<const float4*>(base + 4 * rstride);
    v5 = *reinterpret_cast<const float4*>(base + 5 * rstride);
    v6 = *reinterpret_cast<const float4*>(base + 6 * rstride);
    v7 = *reinterpret_cast<const float4*>(base + 7 * rstride);
    v8 = *reinterpret_cast<const float4*>(base + 8 * rstride);
    if (xtra) v9 = *reinterpret_cast<const float4*>(base + 9 * rstride);
  };

  // stage each pre-loaded row through LDS, cross-lane gather at labels,
  // exp(+BOOST), write 256B compact row into ring[cc&1].
  auto storebuf = [&](int cc, const float4& v0, const float4& v1,
                      const float4& v2, const float4& v3, const float4& v4,
                      const float4& v5, const float4& v6, const float4& v7,
                      const float4& v8, const float4& v9) {
#define USEJ(VJ, J)                                                          \
    {                                                                        \
      float (&buf)[C] = stage[gw][(J) & 1];                                  \
      *reinterpret_cast<float4*>(&buf[lane * 4]) = VJ;                       \
      const float g = buf[lab];        /* same-wave ds_write->ds_read */     \
      ring[cc & 1][row0 + (J)][lane] = __expf(g + BOOST);                    \
    }
    USEJ(v0, 0) USEJ(v1, 1) USEJ(v2, 2) USEJ(v3, 3) USEJ(v4, 4)
    USEJ(v5, 5) USEJ(v6, 6) USEJ(v7, 7) USEJ(v8, 8)
    if (xtra) USEJ(v9, 9)
#undef USEJ
  };

#define LOADA(CC) loadbuf((CC), uA0, uA1, uA2, uA3, uA4, uA5, uA6, uA7, uA8, uA9)
#define LOADB(CC) loadbuf((CC), uB0, uB1, uB2, uB3, uB4, uB5, uB6, uB7, uB8, uB9)
#define STOREA(CC) storebuf((CC), uA0, uA1, uA2, uA3, uA4, uA5, uA6, uA7, uA8, uA9)
#define STOREB(CC) storebuf((CC), uB0, uB1, uB2, uB3, uB4, uB5, uB6, uB7, uB8, uB9)

  // alpha0 in linear space (no boost at t=0): only lane 0 live.
  const float* nbase = lp + (size_t)n * C;
  float a0 = (lane == 0) ? __expf(nbase[0])   : 0.0f;
  float a1 = (lane == 0) ? __expf(nbase[lab]) : 0.0f;
  float logscale = 0.0f;

  // chain for one 64-row chunk from ring[c&1]
  auto chain = [&](int c) {
    const float* pb = &ring[c & 1][0][lane];
    if (c == 0) {                      // t = 1..63 (t=0 slot skipped)
      CHAIN_GROUP(pb,           0, 1);
      CHAIN_GROUP(pb + 16 * 64, 16, 0);
      CHAIN_GROUP(pb + 32 * 64, 32, 0);
      CHAIN_GROUP(pb + 48 * 64, 48, 0);
    } else {                           // t = 64c .. 64c+63
#pragma unroll
      for (int g = 0; g < 4; ++g)
        CHAIN_GROUP(pb + g * 16 * 64, c * CH + g * 16, 0);
    }
  };

  // Prologue: chunk 0 staged from uA; chunk 1 in flight in uB.
  if (wid > 0) { LOADA(0); STOREA(0); LOADB(1); }
  RING_BARRIER();

  // Steady state, two chunks per pair-iteration. Loads issue at phase TOP
  // into the buffer NOT consumed this phase; consumption is next phase.
#pragma unroll 1
  for (int c = 0; c < NCH; c += 2) {
    // phase: chunk c (even) -- load uA(c+2), consume uB(c+1)
    if (wid > 0) {
      if (c + 2 < NCH) LOADA(c + 2);
      STOREB(c + 1);                   // c+1 <= 7 always here
    } else {
      chain(c);
    }
    RING_BARRIER();
    // phase: chunk c+1 (odd) -- load uB(c+3), consume uA(c+2)
    if (wid > 0) {
      if (c + 3 < NCH) LOADB(c + 3);
      if (c + 2 < NCH) STOREA(c + 2);
    } else {
      chain(c + 1);
    }
    RING_BARRIER();
  }

  // tails: alpha[2*tl-1] (lane tl-1, odd slot), alpha[2*tl] (lane tl, even)
  unsigned* flags = reinterpret_cast<unsigned*>(ws) + 256;
  if (wid == 0) {
    const float tail1 = __shfl(a1, tl - 1);
    const float tail2 = __shfl(a0, tl);
    if (lane == 0) {
      const int live = ((Tin < T) ? Tin : T) - 1;  // boosted live steps
      float loss = -(__logf(tail1 + tail2) + logscale - BOOST * (float)live);
      if (!(loss <= 1e29f) || isnan(loss)) loss = 0.0f;  // zero_infinity
      loss /= (float)tl;
      // publish through device-scope atomics (cross-XCD coherent point):
      // value first, fence, then flag (release ordering).
      atomicExch(&ws[n], loss);
      __threadfence();
      atomicExch(&flags[n], MAGIC);
    }
  }

  // Block 0: parallel-poll the 256 flags, then reduce. Deadlock-free: only
  // block 0 waits; all writer blocks are independent and exit.
  if (n == 0) {
    const int tid = threadIdx.x;
    if (tid < N) {
      while (atomicAdd(&flags[tid], 0u) != MAGIC)
        __builtin_amdgcn_s_sleep(2);
    }
    __syncthreads();
    float v = 0.0f;
    if (tid < N) v = atomicAdd(&ws[tid], 0.0f);  // coherent-point read
#pragma unroll
    for (int off = 32; off > 0; off >>= 1) v += __shfl_down(v, off);
    if (tid < N && (tid & 63) == 0) partial[tid >> 6] = v;
    __syncthreads();
    if (tid == 0) {
      float s = (partial[0] + partial[1] + partial[2] + partial[3]) / (float)N;
      if (isnan(s) || isinf(s)) s = 0.0f;          // final sanitize()
      out[0] = s;
    }
  }
}

extern "C" void kernel_launch(void* const* d_in, const int* in_sizes, int n_in,
                              void* d_out, int out_size, void* d_ws, size_t ws_size,
                              hipStream_t stream) {
  const float* lp     = (const float*)d_in[0];     // (T, N, C) fp32
  const int*   labels = (const int*)d_in[1];       // (N, S)
  const int*   plen   = (const int*)d_in[2];       // (N,)
  const int*   tlen   = (const int*)d_in[3];       // (N,)
  float* ws  = (float*)d_ws;                       // vals + flags
  float* out = (float*)d_out;                      // scalar

  ctc_fused_kernel<<<N, 512, 0, stream>>>(lp, labels, plen, tlen, ws, out);
}